// Round 1
// baseline (4080.273 us; speedup 1.0000x reference)
//
#include <hip/hip_runtime.h>
#include <math.h>

#define EPS 1e-5f

// sizes
#define B_  128
#define T0_ 512
#define S_  30
#define F_  64
#define L1_ 254
#define L2_ 125
#define L3_ 61
#define L4_ 29
#define BS_ (B_*S_)     // 3840
#define N_  (B_*L4_)    // 3712
#define H_  128
#define NC_ 18
#define KFS 1920        // F_*S_

// ---------------- conv0 + conv1 fused (per (b,s) 1-D signal) ----------------
__global__ __launch_bounds__(512) void conv01_kernel(
    const float* __restrict__ x,  const float* __restrict__ w0,
    const float* __restrict__ w1, const float* __restrict__ cb,
    const float* __restrict__ bg, const float* __restrict__ bb,
    const float* __restrict__ bm, const float* __restrict__ bv,
    float* __restrict__ y1)
{
    __shared__ float xl[T0_];
    __shared__ float y0[F_*L1_];      // 65 KB
    __shared__ float wl[F_*F_*5];     // 80 KB
    int bs = blockIdx.x, b = bs/S_, s = bs%S_;
    int tid = threadIdx.x;
    for (int i = tid; i < T0_; i += 512)      xl[i] = x[(b*T0_ + i)*S_ + s];
    for (int i = tid; i < F_*F_*5; i += 512)  wl[i] = w1[i];
    __syncthreads();
    // conv0 -> relu -> bn0, into LDS
    for (int task = tid; task < F_*L1_; task += 512) {
        int c = task / L1_, ty = task % L1_;
        float a = cb[c];
        #pragma unroll
        for (int kh = 0; kh < 5; kh++) a += w0[c*5+kh] * xl[2*ty+kh];
        a = fmaxf(a, 0.f);
        float inv = bg[c]*rsqrtf(bv[c]+EPS);
        y0[c*L1_+ty] = a*inv + (bb[c] - bm[c]*inv);
    }
    __syncthreads();
    // conv1 -> relu -> bn1, to global
    for (int task = tid; task < 64*32; task += 512) {
        int f = task >> 5, tg = task & 31;
        int t0 = tg*4;
        float a0=0,a1=0,a2=0,a3=0;
        for (int c = 0; c < F_; c++) {
            const float* yr = &y0[c*L1_];
            float xv[11];
            #pragma unroll
            for (int u = 0; u < 11; u++) { int tt = 2*t0+u; xv[u] = (tt < L1_) ? yr[tt] : 0.f; }
            const float* wp = &wl[(f*F_+c)*5];
            float wa=wp[0], wb2=wp[1], wc2=wp[2], wd=wp[3], we=wp[4];
            a0 += wa*xv[0]+wb2*xv[1]+wc2*xv[2]+wd*xv[3]+we*xv[4];
            a1 += wa*xv[2]+wb2*xv[3]+wc2*xv[4]+wd*xv[5]+we*xv[6];
            a2 += wa*xv[4]+wb2*xv[5]+wc2*xv[6]+wd*xv[7]+we*xv[8];
            a3 += wa*xv[6]+wb2*xv[7]+wc2*xv[8]+wd*xv[9]+we*xv[10];
        }
        float bias = cb[64+f];
        float inv  = bg[64+f]*rsqrtf(bv[64+f]+EPS);
        float add  = bb[64+f] - bm[64+f]*inv;
        float ac[4] = {a0,a1,a2,a3};
        #pragma unroll
        for (int j = 0; j < 4; j++) {
            int t = t0 + j;
            if (t < L2_) y1[(bs*F_+f)*L2_ + t] = fmaxf(ac[j]+bias, 0.f)*inv + add;
        }
    }
}

// ---------------- generic conv layer (conv2 / conv3) ----------------
template<int LIN, int LOUT, int LAYER>
__global__ __launch_bounds__(512) void convk_kernel(
    const float* __restrict__ yin_g, const float* __restrict__ w,
    const float* __restrict__ cb, const float* __restrict__ bg,
    const float* __restrict__ bb, const float* __restrict__ bm,
    const float* __restrict__ bv, float* __restrict__ yout)
{
    __shared__ float yin[F_*LIN];
    __shared__ float wl[F_*F_*5];
    int bs = blockIdx.x, tid = threadIdx.x;
    for (int i = tid; i < F_*LIN; i += 512)  yin[i] = yin_g[bs*F_*LIN + i];
    for (int i = tid; i < F_*F_*5; i += 512) wl[i]  = w[i];
    __syncthreads();
    const int NG = (LOUT+3)/4;
    for (int task = tid; task < F_*NG; task += 512) {
        int f = task / NG, tg = task % NG, t0 = tg*4;
        float acc[4] = {0,0,0,0};
        for (int c = 0; c < F_; c++) {
            const float* yr = &yin[c*LIN];
            float xv[11];
            #pragma unroll
            for (int u = 0; u < 11; u++) { int tt = 2*t0+u; xv[u] = (tt < LIN) ? yr[tt] : 0.f; }
            const float* wp = &wl[(f*F_+c)*5];
            #pragma unroll
            for (int j = 0; j < 4; j++) {
                float a = 0.f;
                #pragma unroll
                for (int kh = 0; kh < 5; kh++) a += wp[kh]*xv[2*j+kh];
                acc[j] += a;
            }
        }
        float bias = cb[LAYER*64+f];
        float inv  = bg[LAYER*64+f]*rsqrtf(bv[LAYER*64+f]+EPS);
        float add  = bb[LAYER*64+f] - bm[LAYER*64+f]*inv;
        #pragma unroll
        for (int j = 0; j < 4; j++) {
            int t = t0 + j;
            if (t < LOUT) yout[(bs*F_+f)*LOUT + t] = fmaxf(acc[j]+bias, 0.f)*inv + add;
        }
    }
}

// ---------------- y3 (b,s,f,l) -> xs (n=(b,l), f, s) tiled transpose ----------------
__global__ __launch_bounds__(256) void transp_kernel(
    const float* __restrict__ y3, float* __restrict__ xs)
{
    __shared__ float tl[15*F_*L4_];   // 27840 floats = 111 KB
    int b = blockIdx.x >> 1, s0 = (blockIdx.x & 1)*15;
    int tid = threadIdx.x;
    const float* src = y3 + (b*S_ + s0)*F_*L4_;
    for (int i = tid; i < 15*F_*L4_; i += 256) tl[i] = src[i];
    __syncthreads();
    for (int i = tid; i < L4_*F_*15; i += 256) {
        int l = i/(F_*15), f = (i/15)%F_, ss = i%15;
        xs[((b*L4_+l)*F_+f)*S_ + s0+ss] = tl[(ss*F_+f)*L4_ + l];
    }
}

// ---------------- self-attention per n slice ----------------
__global__ __launch_bounds__(256) void attn_kernel(
    const float* __restrict__ xsg, const float* __restrict__ wq,
    const float* __restrict__ wk,  const float* __restrict__ wv,
    const float* __restrict__ gam, float* __restrict__ seq)
{
    __shared__ float X[F_][32], Q[F_][32], Kk[F_][32], V[F_][32];
    __shared__ float SC[S_][33];
    __shared__ float cm[S_], cs[S_];
    int n = blockIdx.x, tid = threadIdx.x;
    for (int i = tid; i < KFS; i += 256) X[i/S_][i%S_] = xsg[n*KFS + i];
    __syncthreads();
    for (int task = tid; task < 3*KFS; task += 256) {
        int wsel = task / KFS, r = task % KFS, o = r/S_, si = r%S_;
        const float* W = (wsel==0) ? wq : (wsel==1) ? wk : wv;
        float a = 0.f;
        for (int f = 0; f < F_; f++) a += W[o*F_+f]*X[f][si];
        if (wsel==0) Q[o][si]=a; else if (wsel==1) Kk[o][si]=a; else V[o][si]=a;
    }
    __syncthreads();
    for (int task = tid; task < S_*S_; task += 256) {
        int i = task/S_, jj = task%S_;
        float a = 0.f;
        for (int o = 0; o < F_; o++) a += Q[o][i]*Kk[o][jj];
        SC[i][jj] = a;
    }
    __syncthreads();
    if (tid < S_) {
        int jj = tid; float m = -1e30f;
        for (int i = 0; i < S_; i++) m = fmaxf(m, SC[i][jj]);
        float ssum = 0.f;
        for (int i = 0; i < S_; i++) ssum += expf(SC[i][jj]-m);
        cm[jj] = m; cs[jj] = 1.f/ssum;
    }
    __syncthreads();
    for (int task = tid; task < S_*S_; task += 256) {
        int i = task/S_, jj = task%S_;
        SC[i][jj] = expf(SC[i][jj]-cm[jj])*cs[jj];
    }
    __syncthreads();
    float g = gam[0];
    for (int task = tid; task < KFS; task += 256) {
        int f = task/S_, jj = task%S_;
        float a = 0.f;
        for (int i = 0; i < S_; i++) a += V[f][i]*SC[i][jj];
        seq[n*KFS + task] = g*a + X[f][jj];
    }
}

// ---------------- FC1: (3712,1920) @ (1920,128)^T + relu ----------------
__global__ __launch_bounds__(256) void fc1_kernel(
    const float* __restrict__ seq, const float* __restrict__ w,
    const float* __restrict__ bias, float* __restrict__ out)
{
    __shared__ float Sm[8*KFS];   // 61.4 KB
    int n0 = blockIdx.x*8, tid = threadIdx.x;
    for (int i = tid; i < 8*KFS; i += 256) Sm[i] = seq[n0*KFS + i];
    __syncthreads();
    int h = tid & 127, rp = tid >> 7;
    float acc[4] = {0,0,0,0};
    const float4* wp = (const float4*)(w + h*KFS);
    #pragma unroll 4
    for (int k = 0; k < KFS/4; k++) {
        float4 wvv = wp[k];
        #pragma unroll
        for (int j = 0; j < 4; j++) {
            float4 sv = ((const float4*)&Sm[(rp*4+j)*KFS])[k];
            acc[j] += wvv.x*sv.x + wvv.y*sv.y + wvv.z*sv.z + wvv.w*sv.w;
        }
    }
    float bb2 = bias[h];
    #pragma unroll
    for (int j = 0; j < 4; j++)
        out[(n0 + rp*4 + j)*H_ + h] = fmaxf(acc[j] + bb2, 0.f);
}

// ---------------- 2-layer GRU (one block per batch element) + pred head ----------------
__global__ __launch_bounds__(768) void gru_kernel(
    const float* __restrict__ xin,  const float* __restrict__ wih,
    const float* __restrict__ whh,  const float* __restrict__ bih,
    const float* __restrict__ bhh,  const float* __restrict__ pw,
    const float* __restrict__ pb,   float* __restrict__ out)
{
    __shared__ float xh[H_], hh[H_], gi[3*H_], gh[3*H_], ys[L4_][H_];
    int b = blockIdx.x, tid = threadIdx.x;
    int mat = tid / 384, j = tid % 384;     // mat=0: wih row, mat=1: whh row
    float4 wr[32];                          // full 128-float weight row in VGPRs
    for (int layer = 0; layer < 2; layer++) {
        const float* wsrc = (mat ? whh : wih) + layer*384*128 + j*128;
        #pragma unroll
        for (int u = 0; u < 32; u++) wr[u] = ((const float4*)wsrc)[u];
        float bias = (mat ? bhh : bih)[layer*384 + j];
        if (tid < H_) hh[tid] = 0.f;
        __syncthreads();
        for (int t = 0; t < L4_; t++) {
            if (tid < H_) xh[tid] = (layer == 0) ? xin[(b*L4_+t)*H_ + tid] : ys[t][tid];
            __syncthreads();
            const float* src = mat ? hh : xh;
            float a0=0,a1=0,a2=0,a3=0;
            #pragma unroll
            for (int u = 0; u < 32; u++) {
                float4 xv = ((const float4*)src)[u];   // all-lane LDS broadcast
                a0 += wr[u].x*xv.x; a1 += wr[u].y*xv.y;
                a2 += wr[u].z*xv.z; a3 += wr[u].w*xv.w;
            }
            float g = (a0+a1)+(a2+a3) + bias;
            if (mat) gh[j] = g; else gi[j] = g;
            __syncthreads();
            if (tid < H_) {
                int m = tid;
                float r = 1.f/(1.f+expf(-(gi[m]      + gh[m])));
                float z = 1.f/(1.f+expf(-(gi[m+128]  + gh[m+128])));
                float n = tanhf(gi[m+256] + r*gh[m+256]);
                float hnew = (1.f-z)*n + z*hh[m];
                hh[m] = hnew; ys[t][m] = hnew;
            }
            __syncthreads();
        }
    }
    if (tid < NC_) {
        float a = pb[tid];
        for (int k = 0; k < H_; k++) a += pw[tid*H_+k]*hh[k];
        out[b*NC_ + tid] = a;
    }
}

extern "C" void kernel_launch(void* const* d_in, const int* in_sizes, int n_in,
                              void* d_out, int out_size, void* d_ws, size_t ws_size,
                              hipStream_t stream) {
    const float* x    = (const float*)d_in[0];
    const float* w0   = (const float*)d_in[1];
    const float* wcs  = (const float*)d_in[2];
    const float* cb   = (const float*)d_in[3];
    const float* bg   = (const float*)d_in[4];
    const float* bb   = (const float*)d_in[5];
    const float* bm   = (const float*)d_in[6];
    const float* bv   = (const float*)d_in[7];
    const float* wq   = (const float*)d_in[8];
    const float* wk   = (const float*)d_in[9];
    const float* wv   = (const float*)d_in[10];
    const float* gam  = (const float*)d_in[11];
    const float* fw   = (const float*)d_in[12];
    const float* fb   = (const float*)d_in[13];
    const float* gwih = (const float*)d_in[14];
    const float* gwhh = (const float*)d_in[15];
    const float* gbih = (const float*)d_in[16];
    const float* gbhh = (const float*)d_in[17];
    const float* pw   = (const float*)d_in[18];
    const float* pb   = (const float*)d_in[19];
    float* out = (float*)d_out;
    float* ws  = (float*)d_ws;

    // workspace layout (floats), with lifetime-based reuse; peak = 182.8 MB
    float* y1v  = ws;              // 30,720,000 floats
    float* y2v  = ws + 30720000;   // 14,991,360
    float* y3v  = ws;              //  7,127,040 (reuses dead y1)
    float* xsv  = ws +  8000000;   //  7,127,040
    float* seqv = ws + 16000000;   //  7,127,040
    float* f1v  = ws + 24000000;   //    475,136

    conv01_kernel<<<BS_, 512, 0, stream>>>(x, w0, wcs, cb, bg, bb, bm, bv, y1v);
    convk_kernel<L2_, L3_, 2><<<BS_, 512, 0, stream>>>(y1v, wcs + 1*20480, cb, bg, bb, bm, bv, y2v);
    convk_kernel<L3_, L4_, 3><<<BS_, 512, 0, stream>>>(y2v, wcs + 2*20480, cb, bg, bb, bm, bv, y3v);
    transp_kernel<<<2*B_, 256, 0, stream>>>(y3v, xsv);
    attn_kernel<<<N_, 256, 0, stream>>>(xsv, wq, wk, wv, gam, seqv);
    fc1_kernel<<<N_/8, 256, 0, stream>>>(seqv, fw, fb, f1v);
    gru_kernel<<<B_, 768, 0, stream>>>(f1v, gwih, gwhh, gbih, gbhh, pw, pb, out);
}

// Round 2
// 1275.861 us; speedup vs baseline: 3.1981x; 3.1981x over previous
//
#include <hip/hip_runtime.h>
#include <math.h>

#define EPS 1e-5f

// sizes
#define B_  128
#define T0_ 512
#define S_  30
#define F_  64
#define L1_ 254
#define L2_ 125
#define L3_ 61
#define L4_ 29
#define BS_ (B_*S_)     // 3840
#define N_  (B_*L4_)    // 3712
#define H_  128
#define NC_ 18
#define KFS 1920        // F_*S_

// ---------------- conv0 + conv1 fused (per (b,s) 1-D signal) ----------------
// lane = output t, wave-uniform f-group; weights via scalar loads (no LDS tile)
__global__ __launch_bounds__(512) void conv01_kernel(
    const float* __restrict__ x,  const float* __restrict__ w0,
    const float* __restrict__ w1, const float* __restrict__ cb,
    const float* __restrict__ bg, const float* __restrict__ bb,
    const float* __restrict__ bm, const float* __restrict__ bv,
    float* __restrict__ y1)
{
    __shared__ float xl[T0_];
    __shared__ float y0[F_*272];          // row stride 272 (covers reads to 2*127+5=259)
    int bs = blockIdx.x, b = bs/S_, s = bs%S_;
    int tid = threadIdx.x;
    for (int i = tid; i < T0_; i += 512) xl[i] = x[(b*T0_+i)*S_ + s];
    __syncthreads();
    // conv0 -> relu -> bn0 into LDS (c is wave-uniform -> scalar weight loads)
    for (int task = tid; task < F_*256; task += 512) {
        int c = task >> 8, ty = task & 255;
        float val = 0.f;
        if (ty < L1_) {
            float a = cb[c];
            #pragma unroll
            for (int kh = 0; kh < 5; kh++) a += w0[c*5+kh]*xl[2*ty+kh];
            a = fmaxf(a, 0.f);
            float inv = bg[c]*rsqrtf(bv[c]+EPS);
            val = a*inv + (bb[c]-bm[c]*inv);
        }
        y0[c*272+ty] = val;
    }
    for (int i = tid; i < F_*16; i += 512) y0[(i>>4)*272 + 256 + (i&15)] = 0.f;
    __syncthreads();
    // conv1 -> relu -> bn1: lane t (0..127), 4 wave-pair groups x 16 f
    int t = tid & 127;
    int fg = __builtin_amdgcn_readfirstlane(tid >> 7);   // wave-uniform
    float acc[16];
    #pragma unroll
    for (int i = 0; i < 16; i++) acc[i] = 0.f;
    for (int c = 0; c < F_; c++) {
        const float2* yp = (const float2*)&y0[c*272 + 2*t];   // 8B-aligned, stride-2
        float2 p0 = yp[0], p1 = yp[1], p2 = yp[2];
        const float* wc = w1 + fg*16*320 + c*5;               // scalar (wave-uniform)
        #pragma unroll
        for (int fi = 0; fi < 16; fi++) {
            const float* wp = wc + fi*320;
            acc[fi] += wp[0]*p0.x + wp[1]*p0.y + wp[2]*p1.x + wp[3]*p1.y + wp[4]*p2.x;
        }
    }
    if (t < L2_) {
        #pragma unroll
        for (int fi = 0; fi < 16; fi++) {
            int f = fg*16 + fi;
            float inv = bg[64+f]*rsqrtf(bv[64+f]+EPS);
            float add = bb[64+f]-bm[64+f]*inv;
            y1[(bs*F_+f)*L2_ + t] = fmaxf(acc[fi]+cb[64+f], 0.f)*inv + add;
        }
    }
}

// ---------------- generic conv layer (conv2 / conv3) ----------------
// SLICES batch-slices per block, NT lanes per slice, FPG = 64/(512/(NT*SLICES)) f per group
template<int LIN, int LOUT, int NT, int SLICES, int STRIDE, int LAYER>
__global__ __launch_bounds__(512) void convk_kernel(
    const float* __restrict__ yin_g, const float* __restrict__ w,
    const float* __restrict__ cb, const float* __restrict__ bg,
    const float* __restrict__ bb, const float* __restrict__ bm,
    const float* __restrict__ bv, float* __restrict__ yout)
{
    constexpr int G   = 512/(NT*SLICES);   // f-groups
    constexpr int FPG = F_/G;              // f per group
    __shared__ float yin[SLICES*F_*STRIDE];
    int bs0 = blockIdx.x*SLICES, tid = threadIdx.x;
    for (int i = tid; i < SLICES*F_*STRIDE; i += 512) {
        int l = i % STRIDE, cs = i / STRIDE;          // cs = sl*64 + c
        int sl2 = cs >> 6, c = cs & 63;
        yin[i] = (l < LIN) ? yin_g[((bs0+sl2)*F_ + c)*LIN + l] : 0.f;
    }
    __syncthreads();
    int tt = tid & (NT-1);
    int sl = (tid / NT) & (SLICES-1);
    int fg = __builtin_amdgcn_readfirstlane(tid >> 6);  // NT*SLICES == 64 always
    float acc[FPG];
    #pragma unroll
    for (int i = 0; i < FPG; i++) acc[i] = 0.f;
    const float* base = &yin[sl*F_*STRIDE];
    for (int c = 0; c < F_; c++) {
        const float2* yp = (const float2*)&base[c*STRIDE + 2*tt];
        float2 p0 = yp[0], p1 = yp[1], p2 = yp[2];
        const float* wc = w + fg*FPG*320 + c*5;        // scalar (wave-uniform)
        #pragma unroll
        for (int fi = 0; fi < FPG; fi++) {
            const float* wp = wc + fi*320;
            acc[fi] += wp[0]*p0.x + wp[1]*p0.y + wp[2]*p1.x + wp[3]*p1.y + wp[4]*p2.x;
        }
    }
    if (tt < LOUT) {
        #pragma unroll
        for (int fi = 0; fi < FPG; fi++) {
            int f = fg*FPG + fi;
            float inv = bg[LAYER*64+f]*rsqrtf(bv[LAYER*64+f]+EPS);
            float add = bb[LAYER*64+f]-bm[LAYER*64+f]*inv;
            yout[((bs0+sl)*F_+f)*LOUT + tt] = fmaxf(acc[fi]+cb[LAYER*64+f], 0.f)*inv + add;
        }
    }
}

// ---------------- y3 (b,s,f,l) -> xs (n=(b,l), f, s) tiled transpose ----------------
__global__ __launch_bounds__(256) void transp_kernel(
    const float* __restrict__ y3, float* __restrict__ xs)
{
    __shared__ float tl[15*F_*L4_];   // 27840 floats = 111 KB
    int b = blockIdx.x >> 1, s0 = (blockIdx.x & 1)*15;
    int tid = threadIdx.x;
    const float* src = y3 + (b*S_ + s0)*F_*L4_;
    for (int i = tid; i < 15*F_*L4_; i += 256) tl[i] = src[i];
    __syncthreads();
    for (int i = tid; i < L4_*F_*15; i += 256) {
        int l = i/(F_*15), f = (i/15)%F_, ss = i%15;
        xs[((b*L4_+l)*F_+f)*S_ + s0+ss] = tl[(ss*F_+f)*L4_ + l];
    }
}

// ---------------- self-attention per n slice ----------------
__global__ __launch_bounds__(256) void attn_kernel(
    const float* __restrict__ xsg, const float* __restrict__ wq,
    const float* __restrict__ wk,  const float* __restrict__ wv,
    const float* __restrict__ gam, float* __restrict__ seq)
{
    __shared__ float X[F_][32], Q[F_][32], Kk[F_][32], V[F_][32];
    __shared__ float SC[S_][33];
    __shared__ float cm[S_], cs[S_];
    int n = blockIdx.x, tid = threadIdx.x;
    for (int i = tid; i < KFS; i += 256) X[i/S_][i%S_] = xsg[n*KFS + i];
    __syncthreads();
    for (int task = tid; task < 3*KFS; task += 256) {
        int wsel = task / KFS, r = task % KFS, o = r/S_, si = r%S_;
        const float* W = (wsel==0) ? wq : (wsel==1) ? wk : wv;
        float a = 0.f;
        for (int f = 0; f < F_; f++) a += W[o*F_+f]*X[f][si];
        if (wsel==0) Q[o][si]=a; else if (wsel==1) Kk[o][si]=a; else V[o][si]=a;
    }
    __syncthreads();
    for (int task = tid; task < S_*S_; task += 256) {
        int i = task/S_, jj = task%S_;
        float a = 0.f;
        for (int o = 0; o < F_; o++) a += Q[o][i]*Kk[o][jj];
        SC[i][jj] = a;
    }
    __syncthreads();
    if (tid < S_) {
        int jj = tid; float m = -1e30f;
        for (int i = 0; i < S_; i++) m = fmaxf(m, SC[i][jj]);
        float ssum = 0.f;
        for (int i = 0; i < S_; i++) ssum += expf(SC[i][jj]-m);
        cm[jj] = m; cs[jj] = 1.f/ssum;
    }
    __syncthreads();
    for (int task = tid; task < S_*S_; task += 256) {
        int i = task/S_, jj = task%S_;
        SC[i][jj] = expf(SC[i][jj]-cm[jj])*cs[jj];
    }
    __syncthreads();
    float g = gam[0];
    for (int task = tid; task < KFS; task += 256) {
        int f = task/S_, jj = task%S_;
        float a = 0.f;
        for (int i = 0; i < S_; i++) a += V[f][i]*SC[i][jj];
        seq[n*KFS + task] = g*a + X[f][jj];
    }
}

// ---------------- FC1: (3712,1920) @ (1920,128)^T + relu ----------------
__global__ __launch_bounds__(256) void fc1_kernel(
    const float* __restrict__ seq, const float* __restrict__ w,
    const float* __restrict__ bias, float* __restrict__ out)
{
    __shared__ float Sm[8*KFS];   // 61.4 KB
    int n0 = blockIdx.x*8, tid = threadIdx.x;
    for (int i = tid; i < 8*KFS; i += 256) Sm[i] = seq[n0*KFS + i];
    __syncthreads();
    int h = tid & 127, rp = tid >> 7;
    float acc[4] = {0,0,0,0};
    const float4* wp = (const float4*)(w + h*KFS);
    #pragma unroll 4
    for (int k = 0; k < KFS/4; k++) {
        float4 wvv = wp[k];
        #pragma unroll
        for (int j = 0; j < 4; j++) {
            float4 sv = ((const float4*)&Sm[(rp*4+j)*KFS])[k];
            acc[j] += wvv.x*sv.x + wvv.y*sv.y + wvv.z*sv.z + wvv.w*sv.w;
        }
    }
    float bb2 = bias[h];
    #pragma unroll
    for (int j = 0; j < 4; j++)
        out[(n0 + rp*4 + j)*H_ + h] = fmaxf(acc[j] + bb2, 0.f);
}

// ---------------- 2-layer GRU (one block per batch element) + pred head ----------------
__global__ __launch_bounds__(768) void gru_kernel(
    const float* __restrict__ xin,  const float* __restrict__ wih,
    const float* __restrict__ whh,  const float* __restrict__ bih,
    const float* __restrict__ bhh,  const float* __restrict__ pw,
    const float* __restrict__ pb,   float* __restrict__ out)
{
    __shared__ float xh[H_], hh[H_], gi[3*H_], gh[3*H_], ys[L4_][H_];
    int b = blockIdx.x, tid = threadIdx.x;
    int mat = tid / 384, j = tid % 384;     // mat=0: wih row, mat=1: whh row
    float4 wr[32];                          // full 128-float weight row in VGPRs
    for (int layer = 0; layer < 2; layer++) {
        const float* wsrc = (mat ? whh : wih) + layer*384*128 + j*128;
        #pragma unroll
        for (int u = 0; u < 32; u++) wr[u] = ((const float4*)wsrc)[u];
        float bias = (mat ? bhh : bih)[layer*384 + j];
        if (tid < H_) hh[tid] = 0.f;
        __syncthreads();
        for (int t = 0; t < L4_; t++) {
            if (tid < H_) xh[tid] = (layer == 0) ? xin[(b*L4_+t)*H_ + tid] : ys[t][tid];
            __syncthreads();
            const float* src = mat ? hh : xh;
            float a0=0,a1=0,a2=0,a3=0;
            #pragma unroll
            for (int u = 0; u < 32; u++) {
                float4 xv = ((const float4*)src)[u];   // all-lane LDS broadcast
                a0 += wr[u].x*xv.x; a1 += wr[u].y*xv.y;
                a2 += wr[u].z*xv.z; a3 += wr[u].w*xv.w;
            }
            float g = (a0+a1)+(a2+a3) + bias;
            if (mat) gh[j] = g; else gi[j] = g;
            __syncthreads();
            if (tid < H_) {
                int m = tid;
                float r = 1.f/(1.f+expf(-(gi[m]      + gh[m])));
                float z = 1.f/(1.f+expf(-(gi[m+128]  + gh[m+128])));
                float n = tanhf(gi[m+256] + r*gh[m+256]);
                float hnew = (1.f-z)*n + z*hh[m];
                hh[m] = hnew; ys[t][m] = hnew;
            }
            __syncthreads();
        }
    }
    if (tid < NC_) {
        float a = pb[tid];
        for (int k = 0; k < H_; k++) a += pw[tid*H_+k]*hh[k];
        out[b*NC_ + tid] = a;
    }
}

extern "C" void kernel_launch(void* const* d_in, const int* in_sizes, int n_in,
                              void* d_out, int out_size, void* d_ws, size_t ws_size,
                              hipStream_t stream) {
    const float* x    = (const float*)d_in[0];
    const float* w0   = (const float*)d_in[1];
    const float* wcs  = (const float*)d_in[2];
    const float* cb   = (const float*)d_in[3];
    const float* bg   = (const float*)d_in[4];
    const float* bb   = (const float*)d_in[5];
    const float* bm   = (const float*)d_in[6];
    const float* bv   = (const float*)d_in[7];
    const float* wq   = (const float*)d_in[8];
    const float* wk   = (const float*)d_in[9];
    const float* wv   = (const float*)d_in[10];
    const float* gam  = (const float*)d_in[11];
    const float* fw   = (const float*)d_in[12];
    const float* fb   = (const float*)d_in[13];
    const float* gwih = (const float*)d_in[14];
    const float* gwhh = (const float*)d_in[15];
    const float* gbih = (const float*)d_in[16];
    const float* gbhh = (const float*)d_in[17];
    const float* pw   = (const float*)d_in[18];
    const float* pb   = (const float*)d_in[19];
    float* out = (float*)d_out;
    float* ws  = (float*)d_ws;

    // workspace layout (floats), lifetime-based reuse
    float* y1v  = ws;              // 30,720,000 floats
    float* y2v  = ws + 30720000;   // 14,991,360
    float* y3v  = ws;              //  7,127,040 (reuses dead y1)
    float* xsv  = ws +  8000000;   //  7,127,040
    float* seqv = ws + 16000000;   //  7,127,040
    float* f1v  = ws + 24000000;   //    475,136

    conv01_kernel<<<BS_, 512, 0, stream>>>(x, w0, wcs, cb, bg, bb, bm, bv, y1v);
    // conv2: LIN=125, LOUT=61, NT=64, SLICES=1, STRIDE=136 (reads to 2*63+5=131)
    convk_kernel<L2_, L3_, 64, 1, 136, 2><<<BS_, 512, 0, stream>>>(
        y1v, wcs + 1*20480, cb, bg, bb, bm, bv, y2v);
    // conv3: LIN=61, LOUT=29, NT=32, SLICES=2, STRIDE=72 (reads to 2*31+5=67)
    convk_kernel<L3_, L4_, 32, 2, 72, 3><<<BS_/2, 512, 0, stream>>>(
        y2v, wcs + 2*20480, cb, bg, bb, bm, bv, y3v);
    transp_kernel<<<2*B_, 256, 0, stream>>>(y3v, xsv);
    attn_kernel<<<N_, 256, 0, stream>>>(xsv, wq, wk, wv, gam, seqv);
    fc1_kernel<<<N_/8, 256, 0, stream>>>(seqv, fw, fb, f1v);
    gru_kernel<<<B_, 768, 0, stream>>>(f1v, gwih, gwhh, gbih, gbhh, pw, pb, out);
}

// Round 4
// 1211.882 us; speedup vs baseline: 3.3669x; 1.0528x over previous
//
#include <hip/hip_runtime.h>
#include <math.h>

#define EPS 1e-5f

// sizes
#define B_  128
#define T0_ 512
#define S_  30
#define F_  64
#define L1_ 254
#define L2_ 125
#define L3_ 61
#define L4_ 29
#define BS_ (B_*S_)     // 3840
#define N_  (B_*L4_)    // 3712
#define H_  128
#define NC_ 18
#define KFS 1920        // F_*S_

typedef __attribute__((ext_vector_type(8))) short short8;
typedef __attribute__((ext_vector_type(16))) float f32x16;

__device__ __forceinline__ uint32_t f2bf(float f) {
    uint32_t u = __float_as_uint(f);
    return (u + 0x7fffu + ((u >> 16) & 1u)) >> 16;
}
// pack fp32 -> (bf16_lo << 16) | bf16_hi ; x ~= hi + lo to ~2^-17 rel
__device__ __forceinline__ uint32_t pack_hl(float f) {
    uint32_t h = f2bf(f);
    float hf = __uint_as_float(h << 16);
    uint32_t l = f2bf(f - hf);
    return (l << 16) | h;
}
union Frag { uint32_t u[4]; short8 s; };

// from 5 packed words (elems k=0..4; k=5..7 zero) build hi/lo bf16x8 frags
__device__ __forceinline__ void mk_frags(uint32_t w0, uint32_t w1, uint32_t w2,
                                         uint32_t w3, uint32_t w4,
                                         short8& hi, short8& lo) {
    Frag H, L;
    H.u[0] = __builtin_amdgcn_perm(w1, w0, 0x05040100u);
    H.u[1] = __builtin_amdgcn_perm(w3, w2, 0x05040100u);
    H.u[2] = w4 & 0xffffu;
    H.u[3] = 0u;
    L.u[0] = __builtin_amdgcn_perm(w1, w0, 0x07060302u);
    L.u[1] = __builtin_amdgcn_perm(w3, w2, 0x07060302u);
    L.u[2] = w4 >> 16;
    L.u[3] = 0u;
    hi = H.s; lo = L.s;
}

#define MFMA(a,b,c) __builtin_amdgcn_mfma_f32_32x32x16_bf16(a, b, c, 0, 0, 0)

// one 32f x 32t output tile via split-bf16 MFMA; K' = 64c x 8kh(padded) = 512
// alds: packed weights [f][325] (c*5+kh), blds: packed input row-major [c][STRIDE]
template<int STRIDE, int LOUT, bool PACKOUT>
__device__ __forceinline__ void conv_mfma_tile(
    const uint32_t* __restrict__ alds, const uint32_t* __restrict__ bld,
    int f0, int t0, int lane, int bsidx,
    const float* __restrict__ cbL, const float* __restrict__ bgL,
    const float* __restrict__ bbL, const float* __restrict__ bmL,
    const float* __restrict__ bvL, void* __restrict__ yout, int outstride)
{
    int tcol = lane & 31, chalf = lane >> 5;
    f32x16 acc;
    #pragma unroll
    for (int i = 0; i < 16; i++) acc[i] = 0.f;
    const uint32_t* arow = alds + (uint32_t)(f0 + tcol)*325 + chalf*5;
    const uint32_t* bcol = bld + chalf*STRIDE + 2*(t0 + tcol);
    #pragma unroll 2
    for (int ks = 0; ks < 32; ks++) {
        const uint32_t* ap = arow + ks*10;               // c = 2ks+chalf
        uint32_t a0=ap[0], a1=ap[1], a2=ap[2], a3=ap[3], a4=ap[4];
        short8 AH, AL; mk_frags(a0,a1,a2,a3,a4,AH,AL);
        const uint2* bp = (const uint2*)(bcol + ks*2*STRIDE);
        uint2 q0 = bp[0], q1 = bp[1], q2 = bp[2];
        short8 BH, BL; mk_frags(q0.x,q0.y,q1.x,q1.y,q2.x,BH,BL);
        acc = MFMA(AH, BH, acc);
        acc = MFMA(AH, BL, acc);
        acc = MFMA(AL, BH, acc);
    }
    int t = t0 + tcol;
    if (t < LOUT) {
        #pragma unroll
        for (int r = 0; r < 16; r++) {
            int f = f0 + (r&3) + 8*(r>>2) + 4*chalf;     // verified C/D row map
            float inv = bgL[f]*rsqrtf(bvL[f]+EPS);
            float val = fmaxf(acc[r]+cbL[f], 0.f)*inv + (bbL[f]-bmL[f]*inv);
            if (PACKOUT) ((uint32_t*)yout)[(bsidx*F_+f)*outstride + t] = pack_hl(val);
            else         ((float*)   yout)[(bsidx*F_+f)*outstride + t] = val;
        }
    }
}

// ---------------- conv0 (fp32, exact) + conv1 (MFMA) fused ----------------
__global__ __launch_bounds__(512) void conv01_mfma(
    const float* __restrict__ x,  const float* __restrict__ w0,
    const float* __restrict__ w1, const float* __restrict__ cb,
    const float* __restrict__ bg, const float* __restrict__ bb,
    const float* __restrict__ bm, const float* __restrict__ bv,
    uint32_t* __restrict__ y1p)
{
    __shared__ uint32_t alds[20800];     // weights [f][325] packed   83.2 KB
    __shared__ uint32_t y0p[F_*264];     // conv0 out packed          67.6 KB
    __shared__ float xl[T0_];
    int bs = blockIdx.x, b = bs/S_, s = bs - b*S_;
    int tid = threadIdx.x;
    for (int i = tid; i < 20800; i += 512) {
        int f = i/325, q = i - f*325;
        alds[i] = (q < 320) ? pack_hl(w1[f*320 + q]) : 0u;
    }
    xl[tid] = x[(b*T0_+tid)*S_ + s];
    __syncthreads();
    for (int i = tid; i < F_*264; i += 512) {
        int c = i/264, tp = i - c*264;
        float val = 0.f;
        if (tp < L1_) {
            float a = cb[c];
            #pragma unroll
            for (int kh = 0; kh < 5; kh++) a += w0[c*5+kh]*xl[2*tp+kh];
            a = fmaxf(a, 0.f);
            float inv = bg[c]*rsqrtf(bv[c]+EPS);
            val = a*inv + (bb[c]-bm[c]*inv);
        }
        y0p[i] = pack_hl(val);
    }
    __syncthreads();
    int w = tid>>6, lane = tid&63;
    int ft = w>>2, tt = w&3;             // 2 f-tiles x 4 t-tiles
    conv_mfma_tile<264, L2_, true>(alds, y0p, ft*32, tt*32, lane, bs,
        cb+64, bg+64, bb+64, bm+64, bv+64, y1p, L2_);
}

// ---------------- conv2 / conv3 (MFMA) ----------------
template<int LIN, int LOUT, int STRIDE, int SLICES, int NTT, bool PACKOUT>
__global__ __launch_bounds__(512) void convk_mfma(
    const uint32_t* __restrict__ yin, const float* __restrict__ wL,
    const float* __restrict__ cbL, const float* __restrict__ bgL,
    const float* __restrict__ bbL, const float* __restrict__ bmL,
    const float* __restrict__ bvL, void* __restrict__ yout)
{
    __shared__ uint32_t alds[20800];
    __shared__ uint32_t blds[SLICES*F_*STRIDE];
    int bs0 = blockIdx.x*SLICES, tid = threadIdx.x;
    for (int i = tid; i < 20800; i += 512) {
        int f = i/325, q = i - f*325;
        alds[i] = (q < 320) ? pack_hl(wL[f*320 + q]) : 0u;
    }
    constexpr int TOT = SLICES*F_*STRIDE;
    for (int i = tid; i < TOT; i += 512) {
        int lp = i % STRIDE, cs = i / STRIDE;     // cs = sl*64 + c
        blds[i] = (lp < LIN) ? yin[(bs0*F_ + cs)*LIN + lp] : 0u;
    }
    __syncthreads();
    int w = tid>>6, lane = tid&63;
    constexpr int WPB = 8/SLICES;
    int sl = w / WPB, wloc = w % WPB;
    int ft = wloc / NTT, tt = wloc % NTT;
    conv_mfma_tile<STRIDE, LOUT, PACKOUT>(alds, blds + sl*F_*STRIDE,
        ft*32, tt*32, lane, bs0+sl, cbL, bgL, bbL, bmL, bvL, yout, LOUT);
}

// ---------------- y3 (b,s,f,l) -> xs (n=(b,l), f, s) tiled transpose ----------------
__global__ __launch_bounds__(256) void transp_kernel(
    const float* __restrict__ y3, float* __restrict__ xs)
{
    __shared__ float tl[15*F_*L4_];
    int b = blockIdx.x >> 1, s0 = (blockIdx.x & 1)*15;
    int tid = threadIdx.x;
    const float* src = y3 + (b*S_ + s0)*F_*L4_;
    for (int i = tid; i < 15*F_*L4_; i += 256) tl[i] = src[i];
    __syncthreads();
    for (int i = tid; i < L4_*F_*15; i += 256) {
        int l = i/(F_*15), f = (i/15)%F_, ss = i%15;
        xs[((b*L4_+l)*F_+f)*S_ + s0+ss] = tl[(ss*F_+f)*L4_ + l];
    }
}

// ---------------- self-attention per n slice ----------------
__global__ __launch_bounds__(256) void attn_kernel(
    const float* __restrict__ xsg, const float* __restrict__ wq,
    const float* __restrict__ wk,  const float* __restrict__ wv,
    const float* __restrict__ gam, float* __restrict__ seq)
{
    __shared__ float X[F_][32], Q[F_][32], Kk[F_][32], V[F_][32];
    __shared__ float SC[S_][33];
    __shared__ float cm[S_], cs[S_];
    int n = blockIdx.x, tid = threadIdx.x;
    for (int i = tid; i < KFS; i += 256) X[i/S_][i%S_] = xsg[n*KFS + i];
    __syncthreads();
    for (int task = tid; task < 3*KFS; task += 256) {
        int wsel = task / KFS, r = task % KFS, o = r/S_, si = r%S_;
        const float* W = (wsel==0) ? wq : (wsel==1) ? wk : wv;
        float a = 0.f;
        for (int f = 0; f < F_; f++) a += W[o*F_+f]*X[f][si];
        if (wsel==0) Q[o][si]=a; else if (wsel==1) Kk[o][si]=a; else V[o][si]=a;
    }
    __syncthreads();
    for (int task = tid; task < S_*S_; task += 256) {
        int i = task/S_, jj = task%S_;
        float a = 0.f;
        for (int o = 0; o < F_; o++) a += Q[o][i]*Kk[o][jj];
        SC[i][jj] = a;
    }
    __syncthreads();
    if (tid < S_) {
        int jj = tid; float m = -1e30f;
        for (int i = 0; i < S_; i++) m = fmaxf(m, SC[i][jj]);
        float ssum = 0.f;
        for (int i = 0; i < S_; i++) ssum += expf(SC[i][jj]-m);
        cm[jj] = m; cs[jj] = 1.f/ssum;
    }
    __syncthreads();
    for (int task = tid; task < S_*S_; task += 256) {
        int i = task/S_, jj = task%S_;
        SC[i][jj] = expf(SC[i][jj]-cm[jj])*cs[jj];
    }
    __syncthreads();
    float g = gam[0];
    for (int task = tid; task < KFS; task += 256) {
        int f = task/S_, jj = task%S_;
        float a = 0.f;
        for (int i = 0; i < S_; i++) a += V[f][i]*SC[i][jj];
        seq[n*KFS + task] = g*a + X[f][jj];
    }
}

// ---------------- FC1: (3712,1920) @ (1920,128)^T + relu ----------------
__global__ __launch_bounds__(256) void fc1_kernel(
    const float* __restrict__ seq, const float* __restrict__ w,
    const float* __restrict__ bias, float* __restrict__ out)
{
    __shared__ float Sm[8*KFS];
    int n0 = blockIdx.x*8, tid = threadIdx.x;
    for (int i = tid; i < 8*KFS; i += 256) Sm[i] = seq[n0*KFS + i];
    __syncthreads();
    int h = tid & 127, rp = tid >> 7;
    float acc[4] = {0,0,0,0};
    const float4* wp = (const float4*)(w + h*KFS);
    #pragma unroll 4
    for (int k = 0; k < KFS/4; k++) {
        float4 wvv = wp[k];
        #pragma unroll
        for (int j = 0; j < 4; j++) {
            float4 sv = ((const float4*)&Sm[(rp*4+j)*KFS])[k];
            acc[j] += wvv.x*sv.x + wvv.y*sv.y + wvv.z*sv.z + wvv.w*sv.w;
        }
    }
    float bb2 = bias[h];
    #pragma unroll
    for (int j = 0; j < 4; j++)
        out[(n0 + rp*4 + j)*H_ + h] = fmaxf(acc[j] + bb2, 0.f);
}

// ---------------- 2-layer GRU (one block per batch element) + pred head ----------------
__global__ __launch_bounds__(768) void gru_kernel(
    const float* __restrict__ xin,  const float* __restrict__ wih,
    const float* __restrict__ whh,  const float* __restrict__ bih,
    const float* __restrict__ bhh,  const float* __restrict__ pw,
    const float* __restrict__ pb,   float* __restrict__ out)
{
    __shared__ float xh[H_], hh[H_], gi[3*H_], gh[3*H_], ys[L4_][H_];
    int b = blockIdx.x, tid = threadIdx.x;
    int mat = tid / 384, j = tid % 384;
    float4 wr[32];
    for (int layer = 0; layer < 2; layer++) {
        const float* wsrc = (mat ? whh : wih) + layer*384*128 + j*128;
        #pragma unroll
        for (int u = 0; u < 32; u++) wr[u] = ((const float4*)wsrc)[u];
        float bias = (mat ? bhh : bih)[layer*384 + j];
        if (tid < H_) hh[tid] = 0.f;
        __syncthreads();
        for (int t = 0; t < L4_; t++) {
            if (tid < H_) xh[tid] = (layer == 0) ? xin[(b*L4_+t)*H_ + tid] : ys[t][tid];
            __syncthreads();
            const float* src = mat ? hh : xh;
            float a0=0,a1=0,a2=0,a3=0;
            #pragma unroll
            for (int u = 0; u < 32; u++) {
                float4 xv = ((const float4*)src)[u];
                a0 += wr[u].x*xv.x; a1 += wr[u].y*xv.y;
                a2 += wr[u].z*xv.z; a3 += wr[u].w*xv.w;
            }
            float g = (a0+a1)+(a2+a3) + bias;
            if (mat) gh[j] = g; else gi[j] = g;
            __syncthreads();
            if (tid < H_) {
                int m = tid;
                float r = 1.f/(1.f+expf(-(gi[m]      + gh[m])));
                float z = 1.f/(1.f+expf(-(gi[m+128]  + gh[m+128])));
                float n = tanhf(gi[m+256] + r*gh[m+256]);
                float hnew = (1.f-z)*n + z*hh[m];
                hh[m] = hnew; ys[t][m] = hnew;
            }
            __syncthreads();
        }
    }
    if (tid < NC_) {
        float a = pb[tid];
        for (int k = 0; k < H_; k++) a += pw[tid*H_+k]*hh[k];
        out[b*NC_ + tid] = a;
    }
}

extern "C" void kernel_launch(void* const* d_in, const int* in_sizes, int n_in,
                              void* d_out, int out_size, void* d_ws, size_t ws_size,
                              hipStream_t stream) {
    const float* x    = (const float*)d_in[0];
    const float* w0   = (const float*)d_in[1];
    const float* wcs  = (const float*)d_in[2];
    const float* cb   = (const float*)d_in[3];
    const float* bg   = (const float*)d_in[4];
    const float* bb   = (const float*)d_in[5];
    const float* bm   = (const float*)d_in[6];
    const float* bv   = (const float*)d_in[7];
    const float* wq   = (const float*)d_in[8];
    const float* wk   = (const float*)d_in[9];
    const float* wv   = (const float*)d_in[10];
    const float* gam  = (const float*)d_in[11];
    const float* fw   = (const float*)d_in[12];
    const float* fb   = (const float*)d_in[13];
    const float* gwih = (const float*)d_in[14];
    const float* gwhh = (const float*)d_in[15];
    const float* gbih = (const float*)d_in[16];
    const float* gbhh = (const float*)d_in[17];
    const float* pw   = (const float*)d_in[18];
    const float* pb   = (const float*)d_in[19];
    float* out = (float*)d_out;

    // workspace (4B units), lifetime-based reuse; peak 45,711,360 words (same as R2)
    uint32_t* wsu  = (uint32_t*)d_ws;
    uint32_t* y1p  = wsu;                  // 3840*64*125 = 30,720,000 (packed hi/lo)
    uint32_t* y2p  = wsu + 30720000;       // 3840*64*61  = 14,991,360 (packed)
    float*    y3v  = (float*)wsu;          //  7,127,040 fp32 (reuses dead y1p)
    float*    xsv  = (float*)(wsu +  8000000);
    float*    seqv = (float*)(wsu + 16000000);
    float*    f1v  = (float*)(wsu + 24000000);

    conv01_mfma<<<BS_, 512, 0, stream>>>(x, w0, wcs, cb, bg, bb, bm, bv, y1p);
    // conv2: LIN=125, LOUT=61, STRIDE=136, SLICES=2, NTT=2, packed out
    convk_mfma<L2_, L3_, 136, 2, 2, true><<<BS_/2, 512, 0, stream>>>(
        y1p, wcs + 20480, cb+128, bg+128, bb+128, bm+128, bv+128, y2p);
    // conv3: LIN=61, LOUT=29, STRIDE=72, SLICES=4, NTT=1, fp32 out
    convk_mfma<L3_, L4_, 72, 4, 1, false><<<BS_/4, 512, 0, stream>>>(
        y2p, wcs + 40960, cb+192, bg+192, bb+192, bm+192, bv+192, y3v);
    transp_kernel<<<2*B_, 256, 0, stream>>>(y3v, xsv);
    attn_kernel<<<N_, 256, 0, stream>>>(xsv, wq, wk, wv, gam, seqv);
    fc1_kernel<<<N_/8, 256, 0, stream>>>(seqv, fw, fb, f1v);
    gru_kernel<<<B_, 768, 0, stream>>>(f1v, gwih, gwhh, gbih, gbhh, pw, pb, out);
}

// Round 5
// 856.758 us; speedup vs baseline: 4.7625x; 1.4145x over previous
//
#include <hip/hip_runtime.h>
#include <math.h>

#define EPS 1e-5f

// sizes
#define B_  128
#define T0_ 512
#define S_  30
#define F_  64
#define L1_ 254
#define L2_ 125
#define L3_ 61
#define L4_ 29
#define BS_ (B_*S_)     // 3840
#define N_  (B_*L4_)    // 3712
#define H_  128
#define NC_ 18
#define KFS 1920        // F_*S_

typedef __attribute__((ext_vector_type(8))) short short8;
typedef __attribute__((ext_vector_type(16))) float f32x16;

__device__ __forceinline__ uint32_t f2bf(float f) {
    uint32_t u = __float_as_uint(f);
    return (u + 0x7fffu + ((u >> 16) & 1u)) >> 16;
}

typedef const __attribute__((address_space(1))) uint32_t* gas_t;
typedef __attribute__((address_space(3))) uint32_t* las_t;
__device__ __forceinline__ void glds16(const void* g, void* l) {
    __builtin_amdgcn_global_load_lds((gas_t)g, (las_t)l, 16, 0, 0);
}

#define MFMA(a,b,c) __builtin_amdgcn_mfma_f32_32x32x16_bf16(a, b, c, 0, 0, 0)

// ---------------- weight prepack: frag-ready hi/lo bf16 planes ----------------
// layout per layer (81920 B): hi[20480 ushort] then lo[20480]; elem idx
// r = ((kh*4+ck)*2+chalf)*512 + f*8 + j  with  c = ck*16 + chalf*8 + j
__global__ __launch_bounds__(256) void prepack_kernel(
    const float* __restrict__ wcs, ushort* __restrict__ aw)
{
    int i = blockIdx.x*256 + threadIdx.x;          // 0..61439
    int l = i / 20480, r = i - l*20480;
    int j = r & 7, f = (r >> 3) & 63, g = r >> 9;
    int chalf = g & 1, ck = (g >> 1) & 3, kh = g >> 3;
    int c = ck*16 + chalf*8 + j;
    float w = wcs[l*20480 + f*320 + c*5 + kh];
    uint32_t h = f2bf(w);
    uint32_t lo = f2bf(w - __uint_as_float(h << 16));
    aw[l*40960 + r]         = (ushort)h;
    aw[l*40960 + 20480 + r] = (ushort)lo;
}

// one 32f x 32t tile, K = 64c x 5kh, 3-term split-bf16
__device__ __forceinline__ f32x16 conv_mm(
    const ushort* __restrict__ Ash, const ushort* __restrict__ Bh,
    const ushort* __restrict__ Bl, int f0, int t0, int tcol, int chalf)
{
    f32x16 acc;
    #pragma unroll
    for (int i = 0; i < 16; i++) acc[i] = 0.f;
    int fa = (f0 + tcol)*8;
    int t = t0 + tcol;
    #pragma unroll
    for (int kh = 0; kh < 5; kh++) {
        int tp = 2*t + kh;
        int sw = (tp >> 3) & 7;
        const ushort* brh = Bh + tp*64;
        const ushort* brl = Bl + tp*64;
        #pragma unroll
        for (int ck = 0; ck < 4; ck++) {
            int g = (kh*4+ck)*2 + chalf;
            short8 AH = *(const short8*)(Ash + g*512 + fa);
            short8 AL = *(const short8*)(Ash + 20480 + g*512 + fa);
            int col = (((ck*2+chalf) ^ sw) << 3);
            short8 BH = *(const short8*)(brh + col);
            short8 BL = *(const short8*)(brl + col);
            acc = MFMA(AH, BH, acc);
            acc = MFMA(AH, BL, acc);
            acc = MFMA(AL, BH, acc);
        }
    }
    return acc;
}

// ---------------- conv0 (fp32 exact) + conv1 (MFMA) ----------------
__global__ __launch_bounds__(512) void conv01_mfma(
    const float* __restrict__ x,  const float* __restrict__ w0,
    const ushort* __restrict__ aw, const float* __restrict__ cb,
    const float* __restrict__ bg, const float* __restrict__ bb,
    const float* __restrict__ bm, const float* __restrict__ bv,
    char* __restrict__ y1h, char* __restrict__ y1l)
{
    __shared__ uint32_t Ash_w[20480];      // 80 KB frag-ready weights
    __shared__ ushort Yt[2][264*64];       // transposed act planes, swizzled
    __shared__ float xl[T0_];
    int bs = blockIdx.x, b = bs/S_, s = bs - b*S_;
    int tid = threadIdx.x;
    #pragma unroll
    for (int k = 0; k < 10; k++)
        glds16((const char*)aw + k*8192 + tid*16, (char*)Ash_w + k*8192 + (tid>>6)*1024);
    xl[tid] = x[(b*T0_ + tid)*S_ + s];
    __syncthreads();
    {   // conv0 -> relu -> bn -> hi/lo split into Yt[t'][c^swz]
        int c = tid & 63;
        float w00=w0[c*5], w01=w0[c*5+1], w02=w0[c*5+2], w03=w0[c*5+3], w04=w0[c*5+4];
        float bias = cb[c];
        float inv = bg[c]*rsqrtf(bv[c]+EPS);
        float add = bb[c]-bm[c]*inv;
        for (int tp = (tid>>6); tp < 264; tp += 8) {
            float val = 0.f;
            if (tp < L1_) {
                float a = bias + w00*xl[2*tp] + w01*xl[2*tp+1] + w02*xl[2*tp+2]
                               + w03*xl[2*tp+3] + w04*xl[2*tp+4];
                val = fmaxf(a, 0.f)*inv + add;
            }
            uint32_t h = f2bf(val);
            uint32_t l = f2bf(val - __uint_as_float(h<<16));
            int col = c ^ ((tp>>3 & 7) << 3);
            Yt[0][tp*64 + col] = (ushort)h;
            Yt[1][tp*64 + col] = (ushort)l;
        }
    }
    __syncthreads();
    int lane = tid & 63, wv = tid >> 6;
    int tcol = lane & 31, chalf = lane >> 5;
    int f0 = (wv>>2)*32, t0 = (wv&3)*32;
    f32x16 acc = conv_mm((const ushort*)Ash_w, Yt[0], Yt[1], f0, t0, tcol, chalf);
    __syncthreads();                       // all Yt reads done; reuse as staging
    int t = t0 + tcol;
    if (t < L2_) {
        int swzo = ((t>>1) ^ (t>>3)) & 7;
        #pragma unroll
        for (int rq = 0; rq < 4; rq++) {
            int fb = f0 + 8*rq + 4*chalf;
            uint32_t h[4], l[4];
            #pragma unroll
            for (int j = 0; j < 4; j++) {
                int r = rq*4 + j, f = fb + j;
                float inv = bg[64+f]*rsqrtf(bv[64+f]+EPS);
                float val = fmaxf(acc[r]+cb[64+f], 0.f)*inv + (bb[64+f]-bm[64+f]*inv);
                h[j] = f2bf(val);
                l[j] = f2bf(val - __uint_as_float(h[j]<<16));
            }
            int pos = ((((fb>>3) ^ swzo) << 3) + (fb & 7));
            uint2 H; H.x = h[0] | (h[1]<<16); H.y = h[2] | (h[3]<<16);
            uint2 L; L.x = l[0] | (l[1]<<16); L.y = l[2] | (l[3]<<16);
            *(uint2*)&Yt[0][t*64 + pos] = H;
            *(uint2*)&Yt[1][t*64 + pos] = L;
        }
    }
    __syncthreads();
    for (int i = tid; i < 2000; i += 512) {      // 125 rows x 8 chunks x 2 planes
        int pl = i >= 1000, jj = pl ? i-1000 : i;
        int tr = jj >> 3, p = jj & 7;
        int q = p ^ ((tr>>1) & 7);               // swz^swzo
        uint4 v = *(const uint4*)&Yt[pl][tr*64 + q*8];
        *(uint4*)((pl ? y1l : y1h) + (size_t)bs*16000 + tr*128 + p*16) = v;
    }
}

// ---------------- conv2 (2 slices/block) ----------------
__global__ __launch_bounds__(512) void conv2_mfma(
    const ushort* __restrict__ aw, const float* __restrict__ cb,
    const float* __restrict__ bg, const float* __restrict__ bb,
    const float* __restrict__ bm, const float* __restrict__ bv,
    char* __restrict__ yh, char* __restrict__ yl)
{
    __shared__ uint32_t Ash_w[20480];
    __shared__ ushort Yt[2][2][132*64];    // [slice][plane]
    int bs0 = blockIdx.x*2, tid = threadIdx.x;
    const char* asrc = (const char*)aw + 81920;
    #pragma unroll
    for (int k = 0; k < 10; k++)
        glds16(asrc + k*8192 + tid*16, (char*)Ash_w + k*8192 + (tid>>6)*1024);
    #pragma unroll
    for (int sl = 0; sl < 2; sl++)
        #pragma unroll
        for (int pl = 0; pl < 2; pl++) {
            const char* src = (pl ? yl : yh) + (size_t)(bs0+sl)*16000;
            glds16(src + tid*16,        (char*)&Yt[sl][pl][0] + (tid>>6)*1024);
            glds16(src + 8192 + tid*16, (char*)&Yt[sl][pl][0] + 8192 + (tid>>6)*1024);
        }
    __syncthreads();
    for (int i = tid; i < 4*224; i += 512) {     // zero rows 125..131
        int g = i / 224, w2 = i - g*224;
        ((uint32_t*)&Yt[g>>1][g&1][125*64])[w2] = 0;
    }
    __syncthreads();
    int lane = tid & 63, wv = tid >> 6;
    int tcol = lane & 31, chalf = lane >> 5;
    int sl = wv >> 2, f0 = ((wv>>1)&1)*32, t0 = (wv&1)*32;
    f32x16 acc = conv_mm((const ushort*)Ash_w, Yt[sl][0], Yt[sl][1], f0, t0, tcol, chalf);
    __syncthreads();
    int t = t0 + tcol;
    if (t < L3_) {
        int swzo = ((t>>1) ^ (t>>3)) & 7;
        #pragma unroll
        for (int rq = 0; rq < 4; rq++) {
            int fb = f0 + 8*rq + 4*chalf;
            uint32_t h[4], l[4];
            #pragma unroll
            for (int j = 0; j < 4; j++) {
                int r = rq*4 + j, f = fb + j;
                float inv = bg[128+f]*rsqrtf(bv[128+f]+EPS);
                float val = fmaxf(acc[r]+cb[128+f], 0.f)*inv + (bb[128+f]-bm[128+f]*inv);
                h[j] = f2bf(val);
                l[j] = f2bf(val - __uint_as_float(h[j]<<16));
            }
            int pos = ((((fb>>3) ^ swzo) << 3) + (fb & 7));
            uint2 H; H.x = h[0] | (h[1]<<16); H.y = h[2] | (h[3]<<16);
            uint2 L; L.x = l[0] | (l[1]<<16); L.y = l[2] | (l[3]<<16);
            *(uint2*)&Yt[sl][0][t*64 + pos] = H;
            *(uint2*)&Yt[sl][1][t*64 + pos] = L;
        }
    }
    __syncthreads();
    for (int i = tid; i < 1952; i += 512) {      // 2sl x 2pl x 61 x 8
        int s2 = i / 976, r2 = i - s2*976;
        int pl = r2 >= 488, jj = pl ? r2-488 : r2;
        int tr = jj >> 3, p = jj & 7;
        int q = p ^ ((tr>>1) & 7);
        uint4 v = *(const uint4*)&Yt[s2][pl][tr*64 + q*8];
        *(uint4*)((pl ? yl : yh) + (size_t)(bs0+s2)*16000 + tr*128 + p*16) = v;  // in-place y2
    }
}

// ---------------- conv3 (4 slices/block, fp32 out) ----------------
__global__ __launch_bounds__(512) void conv3_mfma(
    const ushort* __restrict__ aw, const float* __restrict__ cb,
    const float* __restrict__ bg, const float* __restrict__ bb,
    const float* __restrict__ bm, const float* __restrict__ bv,
    const char* __restrict__ yh, const char* __restrict__ yl,
    float* __restrict__ y3)
{
    __shared__ uint32_t Ash_w[20480];
    __shared__ ushort Yt[4][2][68*64];
    int bs0 = blockIdx.x*4, tid = threadIdx.x;
    const char* asrc = (const char*)aw + 163840;
    #pragma unroll
    for (int k = 0; k < 10; k++)
        glds16(asrc + k*8192 + tid*16, (char*)Ash_w + k*8192 + (tid>>6)*1024);
    #pragma unroll
    for (int sl = 0; sl < 4; sl++)
        #pragma unroll
        for (int pl = 0; pl < 2; pl++) {
            const char* src = (pl ? yl : yh) + (size_t)(bs0+sl)*16000;
            glds16(src + tid*16, (char*)&Yt[sl][pl][0] + (tid>>6)*1024);
        }
    __syncthreads();
    for (int i = tid; i < 8*224; i += 512) {     // zero rows 61..67
        int g = i / 224, w2 = i - g*224;
        ((uint32_t*)&Yt[g>>1][g&1][61*64])[w2] = 0;
    }
    __syncthreads();
    int lane = tid & 63, wv = tid >> 6;
    int tcol = lane & 31, chalf = lane >> 5;
    int sl = wv >> 1, f0 = (wv&1)*32;
    f32x16 acc = conv_mm((const ushort*)Ash_w, Yt[sl][0], Yt[sl][1], f0, 0, tcol, chalf);
    int t = tcol;
    if (t < L4_) {
        #pragma unroll
        for (int r = 0; r < 16; r++) {
            int f = f0 + (r&3) + 8*(r>>2) + 4*chalf;
            float inv = bg[192+f]*rsqrtf(bv[192+f]+EPS);
            float val = fmaxf(acc[r]+cb[192+f], 0.f)*inv + (bb[192+f]-bm[192+f]*inv);
            y3[((size_t)(bs0+sl)*F_ + f)*L4_ + t] = val;
        }
    }
}

// ---------------- y3 (b,s,f,l) -> xs (n=(b,l), f, s) tiled transpose ----------------
__global__ __launch_bounds__(256) void transp_kernel(
    const float* __restrict__ y3, float* __restrict__ xs)
{
    __shared__ float tl[15*F_*L4_];
    int b = blockIdx.x >> 1, s0 = (blockIdx.x & 1)*15;
    int tid = threadIdx.x;
    const float* src = y3 + (b*S_ + s0)*F_*L4_;
    for (int i = tid; i < 15*F_*L4_; i += 256) tl[i] = src[i];
    __syncthreads();
    for (int i = tid; i < L4_*F_*15; i += 256) {
        int l = i/(F_*15), f = (i/15)%F_, ss = i%15;
        xs[((b*L4_+l)*F_+f)*S_ + s0+ss] = tl[(ss*F_+f)*L4_ + l];
    }
}

// ---------------- self-attention per n slice ----------------
__global__ __launch_bounds__(256) void attn_kernel(
    const float* __restrict__ xsg, const float* __restrict__ wq,
    const float* __restrict__ wk,  const float* __restrict__ wv,
    const float* __restrict__ gam, float* __restrict__ seq)
{
    __shared__ float X[F_][32], Q[F_][32], Kk[F_][32], V[F_][32];
    __shared__ float SC[S_][33];
    __shared__ float cm[S_], cs[S_];
    int n = blockIdx.x, tid = threadIdx.x;
    for (int i = tid; i < KFS; i += 256) X[i/S_][i%S_] = xsg[n*KFS + i];
    __syncthreads();
    for (int task = tid; task < 3*KFS; task += 256) {
        int wsel = task / KFS, r = task % KFS, o = r/S_, si = r%S_;
        const float* W = (wsel==0) ? wq : (wsel==1) ? wk : wv;
        float a = 0.f;
        for (int f = 0; f < F_; f++) a += W[o*F_+f]*X[f][si];
        if (wsel==0) Q[o][si]=a; else if (wsel==1) Kk[o][si]=a; else V[o][si]=a;
    }
    __syncthreads();
    for (int task = tid; task < S_*S_; task += 256) {
        int i = task/S_, jj = task%S_;
        float a = 0.f;
        for (int o = 0; o < F_; o++) a += Q[o][i]*Kk[o][jj];
        SC[i][jj] = a;
    }
    __syncthreads();
    if (tid < S_) {
        int jj = tid; float m = -1e30f;
        for (int i = 0; i < S_; i++) m = fmaxf(m, SC[i][jj]);
        float ssum = 0.f;
        for (int i = 0; i < S_; i++) ssum += expf(SC[i][jj]-m);
        cm[jj] = m; cs[jj] = 1.f/ssum;
    }
    __syncthreads();
    for (int task = tid; task < S_*S_; task += 256) {
        int i = task/S_, jj = task%S_;
        SC[i][jj] = expf(SC[i][jj]-cm[jj])*cs[jj];
    }
    __syncthreads();
    float g = gam[0];
    for (int task = tid; task < KFS; task += 256) {
        int f = task/S_, jj = task%S_;
        float a = 0.f;
        for (int i = 0; i < S_; i++) a += V[f][i]*SC[i][jj];
        seq[n*KFS + task] = g*a + X[f][jj];
    }
}

// ---------------- FC1: (3712,1920) @ (1920,128)^T + relu ----------------
__global__ __launch_bounds__(256) void fc1_kernel(
    const float* __restrict__ seq, const float* __restrict__ w,
    const float* __restrict__ bias, float* __restrict__ out)
{
    __shared__ float Sm[8*KFS];
    int n0 = blockIdx.x*8, tid = threadIdx.x;
    for (int i = tid; i < 8*KFS; i += 256) Sm[i] = seq[n0*KFS + i];
    __syncthreads();
    int h = tid & 127, rp = tid >> 7;
    float acc[4] = {0,0,0,0};
    const float4* wp = (const float4*)(w + h*KFS);
    #pragma unroll 4
    for (int k = 0; k < KFS/4; k++) {
        float4 wvv = wp[k];
        #pragma unroll
        for (int j = 0; j < 4; j++) {
            float4 sv = ((const float4*)&Sm[(rp*4+j)*KFS])[k];
            acc[j] += wvv.x*sv.x + wvv.y*sv.y + wvv.z*sv.z + wvv.w*sv.w;
        }
    }
    float bb2 = bias[h];
    #pragma unroll
    for (int j = 0; j < 4; j++)
        out[(n0 + rp*4 + j)*H_ + h] = fmaxf(acc[j] + bb2, 0.f);
}

// ---------------- 2-layer GRU + pred head ----------------
__global__ __launch_bounds__(768) void gru_kernel(
    const float* __restrict__ xin,  const float* __restrict__ wih,
    const float* __restrict__ whh,  const float* __restrict__ bih,
    const float* __restrict__ bhh,  const float* __restrict__ pw,
    const float* __restrict__ pb,   float* __restrict__ out)
{
    __shared__ float xh[H_], hh[H_], gi[3*H_], gh[3*H_], ys[L4_][H_];
    int b = blockIdx.x, tid = threadIdx.x;
    int mat = tid / 384, j = tid % 384;
    float4 wr[32];
    for (int layer = 0; layer < 2; layer++) {
        const float* wsrc = (mat ? whh : wih) + layer*384*128 + j*128;
        #pragma unroll
        for (int u = 0; u < 32; u++) wr[u] = ((const float4*)wsrc)[u];
        float bias = (mat ? bhh : bih)[layer*384 + j];
        if (tid < H_) hh[tid] = 0.f;
        __syncthreads();
        for (int t = 0; t < L4_; t++) {
            if (tid < H_) xh[tid] = (layer == 0) ? xin[(b*L4_+t)*H_ + tid] : ys[t][tid];
            __syncthreads();
            const float* src = mat ? hh : xh;
            float a0=0,a1=0,a2=0,a3=0;
            #pragma unroll
            for (int u = 0; u < 32; u++) {
                float4 xv = ((const float4*)src)[u];
                a0 += wr[u].x*xv.x; a1 += wr[u].y*xv.y;
                a2 += wr[u].z*xv.z; a3 += wr[u].w*xv.w;
            }
            float g = (a0+a1)+(a2+a3) + bias;
            if (mat) gh[j] = g; else gi[j] = g;
            __syncthreads();
            if (tid < H_) {
                int m = tid;
                float r = 1.f/(1.f+expf(-(gi[m]      + gh[m])));
                float z = 1.f/(1.f+expf(-(gi[m+128]  + gh[m+128])));
                float n = tanhf(gi[m+256] + r*gh[m+256]);
                float hnew = (1.f-z)*n + z*hh[m];
                hh[m] = hnew; ys[t][m] = hnew;
            }
            __syncthreads();
        }
    }
    if (tid < NC_) {
        float a = pb[tid];
        for (int k = 0; k < H_; k++) a += pw[tid*H_+k]*hh[k];
        out[b*NC_ + tid] = a;
    }
}

extern "C" void kernel_launch(void* const* d_in, const int* in_sizes, int n_in,
                              void* d_out, int out_size, void* d_ws, size_t ws_size,
                              hipStream_t stream) {
    const float* x    = (const float*)d_in[0];
    const float* w0   = (const float*)d_in[1];
    const float* wcs  = (const float*)d_in[2];
    const float* cb   = (const float*)d_in[3];
    const float* bg   = (const float*)d_in[4];
    const float* bb   = (const float*)d_in[5];
    const float* bm   = (const float*)d_in[6];
    const float* bv   = (const float*)d_in[7];
    const float* wq   = (const float*)d_in[8];
    const float* wk   = (const float*)d_in[9];
    const float* wv   = (const float*)d_in[10];
    const float* gam  = (const float*)d_in[11];
    const float* fw   = (const float*)d_in[12];
    const float* fb   = (const float*)d_in[13];
    const float* gwih = (const float*)d_in[14];
    const float* gwhh = (const float*)d_in[15];
    const float* gbih = (const float*)d_in[16];
    const float* gbhh = (const float*)d_in[17];
    const float* pw   = (const float*)d_in[18];
    const float* pb   = (const float*)d_in[19];
    float* out = (float*)d_out;
    uint32_t* wsu = (uint32_t*)d_ws;

    // workspace (4B word offsets):
    // aw (frag weights)       : 0        .. 61440
    // y1h planes (16000B/bs)  : 61440    .. +15,364,096   (y2 written in-place)
    // y1l planes              : 15425536 .. +15,364,096
    // P0 (y3 / seq)           : 30789632 .. +7,127,040
    // P1 (xs / f1)            : 37916672 .. +7,127,040    (end 45,043,712)
    ushort* aw  = (ushort*)wsu;
    char* y1h   = (char*)(wsu + 61440);
    char* y1l   = (char*)(wsu + 15425536);
    float* y3v  = (float*)(wsu + 30789632);
    float* seqv = (float*)(wsu + 30789632);
    float* xsv  = (float*)(wsu + 37916672);
    float* f1v  = (float*)(wsu + 37916672);

    prepack_kernel<<<240, 256, 0, stream>>>(wcs, aw);
    conv01_mfma<<<BS_, 512, 0, stream>>>(x, w0, aw, cb, bg, bb, bm, bv, y1h, y1l);
    conv2_mfma<<<BS_/2, 512, 0, stream>>>(aw, cb, bg, bb, bm, bv, y1h, y1l);
    conv3_mfma<<<BS_/4, 512, 0, stream>>>(aw, cb, bg, bb, bm, bv, y1h, y1l, y3v);
    transp_kernel<<<2*B_, 256, 0, stream>>>(y3v, xsv);
    attn_kernel<<<N_, 256, 0, stream>>>(xsv, wq, wk, wv, gam, seqv);
    fc1_kernel<<<N_/8, 256, 0, stream>>>(seqv, fw, fb, f1v);
    gru_kernel<<<B_, 768, 0, stream>>>(f1v, gwih, gwhh, gbih, gbhh, pw, pb, out);
}

// Round 6
// 719.974 us; speedup vs baseline: 5.6672x; 1.1900x over previous
//
#include <hip/hip_runtime.h>
#include <math.h>

#define EPS 1e-5f

// sizes
#define B_  128
#define T0_ 512
#define S_  30
#define F_  64
#define L1_ 254
#define L2_ 125
#define L3_ 61
#define L4_ 29
#define BS_ (B_*S_)     // 3840
#define N_  (B_*L4_)    // 3712
#define H_  128
#define NC_ 18
#define KFS 1920        // F_*S_

typedef __attribute__((ext_vector_type(8))) short short8;
typedef __attribute__((ext_vector_type(16))) float f32x16;

__device__ __forceinline__ uint32_t f2bf(float f) {
    uint32_t u = __float_as_uint(f);
    return (u + 0x7fffu + ((u >> 16) & 1u)) >> 16;
}

typedef const __attribute__((address_space(1))) uint32_t* gas_t;
typedef __attribute__((address_space(3))) uint32_t* las_t;
__device__ __forceinline__ void glds16(const void* g, void* l) {
    __builtin_amdgcn_global_load_lds((gas_t)g, (las_t)l, 16, 0, 0);
}

#define MFMA(a,b,c) __builtin_amdgcn_mfma_f32_32x32x16_bf16(a, b, c, 0, 0, 0)

// ---------------- weight prepack: frag-ready hi/lo bf16 planes ----------------
// layout per layer (81920 B): hi[20480 ushort] then lo[20480]; elem idx
// r = ((kh*4+ck)*2+chalf)*512 + f*8 + j  with  c = ck*16 + chalf*8 + j
__global__ __launch_bounds__(256) void prepack_kernel(
    const float* __restrict__ wcs, ushort* __restrict__ aw)
{
    int i = blockIdx.x*256 + threadIdx.x;          // 0..61439
    int l = i / 20480, r = i - l*20480;
    int j = r & 7, f = (r >> 3) & 63, g = r >> 9;
    int chalf = g & 1, ck = (g >> 1) & 3, kh = g >> 3;
    int c = ck*16 + chalf*8 + j;
    float w = wcs[l*20480 + f*320 + c*5 + kh];
    uint32_t h = f2bf(w);
    uint32_t lo = f2bf(w - __uint_as_float(h << 16));
    aw[l*40960 + r]         = (ushort)h;
    aw[l*40960 + 20480 + r] = (ushort)lo;
}

// one 32f x 32t tile, K = 64c x 5kh, 3-term split-bf16
__device__ __forceinline__ f32x16 conv_mm(
    const ushort* __restrict__ Ash, const ushort* __restrict__ Bh,
    const ushort* __restrict__ Bl, int f0, int t0, int tcol, int chalf)
{
    f32x16 acc;
    #pragma unroll
    for (int i = 0; i < 16; i++) acc[i] = 0.f;
    int fa = (f0 + tcol)*8;
    int t = t0 + tcol;
    #pragma unroll
    for (int kh = 0; kh < 5; kh++) {
        int tp = 2*t + kh;
        int sw = (tp >> 3) & 7;
        const ushort* brh = Bh + tp*64;
        const ushort* brl = Bl + tp*64;
        #pragma unroll
        for (int ck = 0; ck < 4; ck++) {
            int g = (kh*4+ck)*2 + chalf;
            short8 AH = *(const short8*)(Ash + g*512 + fa);
            short8 AL = *(const short8*)(Ash + 20480 + g*512 + fa);
            int col = (((ck*2+chalf) ^ sw) << 3);
            short8 BH = *(const short8*)(brh + col);
            short8 BL = *(const short8*)(brl + col);
            acc = MFMA(AH, BH, acc);
            acc = MFMA(AH, BL, acc);
            acc = MFMA(AL, BH, acc);
        }
    }
    return acc;
}

// ---------------- conv0 (fp32 exact) + conv1 (MFMA) ----------------
__global__ __launch_bounds__(512) void conv01_mfma(
    const float* __restrict__ x,  const float* __restrict__ w0,
    const ushort* __restrict__ aw, const float* __restrict__ cb,
    const float* __restrict__ bg, const float* __restrict__ bb,
    const float* __restrict__ bm, const float* __restrict__ bv,
    char* __restrict__ y1h, char* __restrict__ y1l)
{
    __shared__ uint32_t Ash_w[20480];      // 80 KB frag-ready weights
    __shared__ ushort Yt[2][264*64];       // transposed act planes, swizzled
    __shared__ float xl[T0_];
    int bs = blockIdx.x, b = bs/S_, s = bs - b*S_;
    int tid = threadIdx.x;
    #pragma unroll
    for (int k = 0; k < 10; k++)
        glds16((const char*)aw + k*8192 + tid*16, (char*)Ash_w + k*8192 + (tid>>6)*1024);
    xl[tid] = x[(b*T0_ + tid)*S_ + s];
    __syncthreads();
    {   // conv0 -> relu -> bn -> hi/lo split into Yt[t'][c^swz]
        int c = tid & 63;
        float w00=w0[c*5], w01=w0[c*5+1], w02=w0[c*5+2], w03=w0[c*5+3], w04=w0[c*5+4];
        float bias = cb[c];
        float inv = bg[c]*rsqrtf(bv[c]+EPS);
        float add = bb[c]-bm[c]*inv;
        for (int tp = (tid>>6); tp < 264; tp += 8) {
            float val = 0.f;
            if (tp < L1_) {
                float a = bias + w00*xl[2*tp] + w01*xl[2*tp+1] + w02*xl[2*tp+2]
                               + w03*xl[2*tp+3] + w04*xl[2*tp+4];
                val = fmaxf(a, 0.f)*inv + add;
            }
            uint32_t h = f2bf(val);
            uint32_t l = f2bf(val - __uint_as_float(h<<16));
            int col = c ^ ((tp>>3 & 7) << 3);
            Yt[0][tp*64 + col] = (ushort)h;
            Yt[1][tp*64 + col] = (ushort)l;
        }
    }
    __syncthreads();
    int lane = tid & 63, wv = tid >> 6;
    int tcol = lane & 31, chalf = lane >> 5;
    int f0 = (wv>>2)*32, t0 = (wv&3)*32;
    f32x16 acc = conv_mm((const ushort*)Ash_w, Yt[0], Yt[1], f0, t0, tcol, chalf);
    __syncthreads();                       // all Yt reads done; reuse as staging
    int t = t0 + tcol;
    if (t < L2_) {
        int swzo = ((t>>1) ^ (t>>3)) & 7;
        #pragma unroll
        for (int rq = 0; rq < 4; rq++) {
            int fb = f0 + 8*rq + 4*chalf;
            uint32_t h[4], l[4];
            #pragma unroll
            for (int j = 0; j < 4; j++) {
                int r = rq*4 + j, f = fb + j;
                float inv = bg[64+f]*rsqrtf(bv[64+f]+EPS);
                float val = fmaxf(acc[r]+cb[64+f], 0.f)*inv + (bb[64+f]-bm[64+f]*inv);
                h[j] = f2bf(val);
                l[j] = f2bf(val - __uint_as_float(h[j]<<16));
            }
            int pos = ((((fb>>3) ^ swzo) << 3) + (fb & 7));
            uint2 H; H.x = h[0] | (h[1]<<16); H.y = h[2] | (h[3]<<16);
            uint2 L; L.x = l[0] | (l[1]<<16); L.y = l[2] | (l[3]<<16);
            *(uint2*)&Yt[0][t*64 + pos] = H;
            *(uint2*)&Yt[1][t*64 + pos] = L;
        }
    }
    __syncthreads();
    for (int i = tid; i < 2000; i += 512) {      // 125 rows x 8 chunks x 2 planes
        int pl = i >= 1000, jj = pl ? i-1000 : i;
        int tr = jj >> 3, p = jj & 7;
        int q = p ^ ((tr>>1) & 7);               // swz^swzo
        uint4 v = *(const uint4*)&Yt[pl][tr*64 + q*8];
        *(uint4*)((pl ? y1l : y1h) + (size_t)bs*16000 + tr*128 + p*16) = v;
    }
}

// ---------------- conv2 (2 slices/block) ----------------
__global__ __launch_bounds__(512) void conv2_mfma(
    const ushort* __restrict__ aw, const float* __restrict__ cb,
    const float* __restrict__ bg, const float* __restrict__ bb,
    const float* __restrict__ bm, const float* __restrict__ bv,
    char* __restrict__ yh, char* __restrict__ yl)
{
    __shared__ uint32_t Ash_w[20480];
    __shared__ ushort Yt[2][2][132*64];    // [slice][plane]
    int bs0 = blockIdx.x*2, tid = threadIdx.x;
    const char* asrc = (const char*)aw + 81920;
    #pragma unroll
    for (int k = 0; k < 10; k++)
        glds16(asrc + k*8192 + tid*16, (char*)Ash_w + k*8192 + (tid>>6)*1024);
    #pragma unroll
    for (int sl = 0; sl < 2; sl++)
        #pragma unroll
        for (int pl = 0; pl < 2; pl++) {
            const char* src = (pl ? yl : yh) + (size_t)(bs0+sl)*16000;
            glds16(src + tid*16,        (char*)&Yt[sl][pl][0] + (tid>>6)*1024);
            glds16(src + 8192 + tid*16, (char*)&Yt[sl][pl][0] + 8192 + (tid>>6)*1024);
        }
    __syncthreads();
    for (int i = tid; i < 4*224; i += 512) {     // zero rows 125..131
        int g = i / 224, w2 = i - g*224;
        ((uint32_t*)&Yt[g>>1][g&1][125*64])[w2] = 0;
    }
    __syncthreads();
    int lane = tid & 63, wv = tid >> 6;
    int tcol = lane & 31, chalf = lane >> 5;
    int sl = wv >> 2, f0 = ((wv>>1)&1)*32, t0 = (wv&1)*32;
    f32x16 acc = conv_mm((const ushort*)Ash_w, Yt[sl][0], Yt[sl][1], f0, t0, tcol, chalf);
    __syncthreads();
    int t = t0 + tcol;
    if (t < L3_) {
        int swzo = ((t>>1) ^ (t>>3)) & 7;
        #pragma unroll
        for (int rq = 0; rq < 4; rq++) {
            int fb = f0 + 8*rq + 4*chalf;
            uint32_t h[4], l[4];
            #pragma unroll
            for (int j = 0; j < 4; j++) {
                int r = rq*4 + j, f = fb + j;
                float inv = bg[128+f]*rsqrtf(bv[128+f]+EPS);
                float val = fmaxf(acc[r]+cb[128+f], 0.f)*inv + (bb[128+f]-bm[128+f]*inv);
                h[j] = f2bf(val);
                l[j] = f2bf(val - __uint_as_float(h[j]<<16));
            }
            int pos = ((((fb>>3) ^ swzo) << 3) + (fb & 7));
            uint2 H; H.x = h[0] | (h[1]<<16); H.y = h[2] | (h[3]<<16);
            uint2 L; L.x = l[0] | (l[1]<<16); L.y = l[2] | (l[3]<<16);
            *(uint2*)&Yt[sl][0][t*64 + pos] = H;
            *(uint2*)&Yt[sl][1][t*64 + pos] = L;
        }
    }
    __syncthreads();
    for (int i = tid; i < 1952; i += 512) {      // 2sl x 2pl x 61 x 8
        int s2 = i / 976, r2 = i - s2*976;
        int pl = r2 >= 488, jj = pl ? r2-488 : r2;
        int tr = jj >> 3, p = jj & 7;
        int q = p ^ ((tr>>1) & 7);
        uint4 v = *(const uint4*)&Yt[s2][pl][tr*64 + q*8];
        *(uint4*)((pl ? yl : yh) + (size_t)(bs0+s2)*16000 + tr*128 + p*16) = v;  // in-place y2
    }
}

// ---------------- conv3 (4 slices/block, fp32 out) ----------------
__global__ __launch_bounds__(512) void conv3_mfma(
    const ushort* __restrict__ aw, const float* __restrict__ cb,
    const float* __restrict__ bg, const float* __restrict__ bb,
    const float* __restrict__ bm, const float* __restrict__ bv,
    const char* __restrict__ yh, const char* __restrict__ yl,
    float* __restrict__ y3)
{
    __shared__ uint32_t Ash_w[20480];
    __shared__ ushort Yt[4][2][68*64];
    int bs0 = blockIdx.x*4, tid = threadIdx.x;
    const char* asrc = (const char*)aw + 163840;
    #pragma unroll
    for (int k = 0; k < 10; k++)
        glds16(asrc + k*8192 + tid*16, (char*)Ash_w + k*8192 + (tid>>6)*1024);
    #pragma unroll
    for (int sl = 0; sl < 4; sl++)
        #pragma unroll
        for (int pl = 0; pl < 2; pl++) {
            const char* src = (pl ? yl : yh) + (size_t)(bs0+sl)*16000;
            glds16(src + tid*16, (char*)&Yt[sl][pl][0] + (tid>>6)*1024);
        }
    __syncthreads();
    for (int i = tid; i < 8*224; i += 512) {     // zero rows 61..67
        int g = i / 224, w2 = i - g*224;
        ((uint32_t*)&Yt[g>>1][g&1][61*64])[w2] = 0;
    }
    __syncthreads();
    int lane = tid & 63, wv = tid >> 6;
    int tcol = lane & 31, chalf = lane >> 5;
    int sl = wv >> 1, f0 = (wv&1)*32;
    f32x16 acc = conv_mm((const ushort*)Ash_w, Yt[sl][0], Yt[sl][1], f0, 0, tcol, chalf);
    int t = tcol;
    if (t < L4_) {
        #pragma unroll
        for (int r = 0; r < 16; r++) {
            int f = f0 + (r&3) + 8*(r>>2) + 4*chalf;
            float inv = bg[192+f]*rsqrtf(bv[192+f]+EPS);
            float val = fmaxf(acc[r]+cb[192+f], 0.f)*inv + (bb[192+f]-bm[192+f]*inv);
            y3[((size_t)(bs0+sl)*F_ + f)*L4_ + t] = val;
        }
    }
}

// ---------------- y3 (b,s,f,l) -> xs (n=(b,l), f, s) tiled transpose ----------------
__global__ __launch_bounds__(256) void transp_kernel(
    const float* __restrict__ y3, float* __restrict__ xs)
{
    __shared__ float tl[15*F_*L4_];
    int b = blockIdx.x >> 1, s0 = (blockIdx.x & 1)*15;
    int tid = threadIdx.x;
    const float* src = y3 + (b*S_ + s0)*F_*L4_;
    for (int i = tid; i < 15*F_*L4_; i += 256) tl[i] = src[i];
    __syncthreads();
    for (int i = tid; i < L4_*F_*15; i += 256) {
        int l = i/(F_*15), f = (i/15)%F_, ss = i%15;
        xs[((b*L4_+l)*F_+f)*S_ + s0+ss] = tl[(ss*F_+f)*L4_ + l];
    }
}

// ---------------- self-attention per n slice (fp32, register-centric) ----------------
// LDS strides of 36 floats: V-row reads <=2-way (free), float4-aligned everywhere.
__global__ __launch_bounds__(256) void attn_kernel(
    const float* __restrict__ xsg, const float* __restrict__ wq,
    const float* __restrict__ wk,  const float* __restrict__ wv,
    const float* __restrict__ gam, float* __restrict__ seq)
{
    __shared__ float X[F_][32];        // 8 KB; cols 30,31 zeroed
    __shared__ float QKV[192][36];     // 27 KB; rows: Q 0..63, K 64..127, V 128..191
    __shared__ float BETA[S_][36];     // 4.2 KB
    int n = blockIdx.x, tid = threadIdx.x;
    for (int i = tid; i < KFS; i += 256) X[i/S_][i%S_] = xsg[n*KFS + i];
    for (int i = tid; i < 128; i += 256) X[i>>1][30 + (i&1)] = 0.f;
    __syncthreads();

    // ---- QKV: thread = output row o (192 active); W row in VGPRs; X broadcast
    if (tid < 192) {
        int wsel = tid >> 6, row = tid & 63;
        const float* W = (wsel==0) ? wq : (wsel==1) ? wk : wv;
        float4 wr_[16];
        #pragma unroll
        for (int u = 0; u < 16; u++) wr_[u] = ((const float4*)(W + row*64))[u];
        float acc[32];
        #pragma unroll
        for (int i = 0; i < 32; i++) acc[i] = 0.f;
        #pragma unroll
        for (int u = 0; u < 16; u++) {
            float4 w4 = wr_[u];
            #pragma unroll
            for (int c = 0; c < 4; c++) {
                float wv_ = (c==0) ? w4.x : (c==1) ? w4.y : (c==2) ? w4.z : w4.w;
                const float4* xr = (const float4*)&X[u*4+c][0];
                #pragma unroll
                for (int q = 0; q < 8; q++) {
                    float4 xq = xr[q];   // same addr all lanes -> broadcast
                    acc[q*4+0] += wv_*xq.x; acc[q*4+1] += wv_*xq.y;
                    acc[q*4+2] += wv_*xq.z; acc[q*4+3] += wv_*xq.w;
                }
            }
        }
        #pragma unroll
        for (int q = 0; q < 8; q++) {
            float4 o4; o4.x=acc[q*4]; o4.y=acc[q*4+1]; o4.z=acc[q*4+2]; o4.w=acc[q*4+3];
            *(float4*)&QKV[tid][q*4] = o4;
        }
    }
    __syncthreads();

    // ---- scores + softmax over i (in registers, shfl-reduce across 8-lane groups)
    if (tid < 240) {
        int j = tid >> 3, iq = tid & 7;       // j<30; i-quad = iq*4..iq*4+3
        float4 s4 = {0.f, 0.f, 0.f, 0.f};
        for (int o = 0; o < 64; o++) {
            float4 q4 = *(const float4*)&QKV[o][iq*4];
            float kv = QKV[64+o][j];
            s4.x += q4.x*kv; s4.y += q4.y*kv; s4.z += q4.z*kv; s4.w += q4.w*kv;
        }
        if (iq == 7) { s4.z = -1e30f; s4.w = -1e30f; }
        float m = fmaxf(fmaxf(s4.x, s4.y), fmaxf(s4.z, s4.w));
        m = fmaxf(m, __shfl_xor(m, 1, 8));
        m = fmaxf(m, __shfl_xor(m, 2, 8));
        m = fmaxf(m, __shfl_xor(m, 4, 8));
        float e0 = expf(s4.x-m), e1 = expf(s4.y-m), e2 = expf(s4.z-m), e3 = expf(s4.w-m);
        if (iq == 7) { e2 = 0.f; e3 = 0.f; }
        float sum = e0+e1+e2+e3;
        sum += __shfl_xor(sum, 1, 8);
        sum += __shfl_xor(sum, 2, 8);
        sum += __shfl_xor(sum, 4, 8);
        float inv = 1.f/sum;
        int i0 = iq*4;
        BETA[i0][j]   = e0*inv;
        BETA[i0+1][j] = e1*inv;
        if (iq < 7) { BETA[i0+2][j] = e2*inv; BETA[i0+3][j] = e3*inv; }
    }
    __syncthreads();

    // ---- PV + residual: thread = (f, j-octet)
    {
        int f = tid >> 2, jh = tid & 3;
        float acc[8];
        #pragma unroll
        for (int i = 0; i < 8; i++) acc[i] = 0.f;
        for (int i = 0; i < S_; i++) {
            float v = QKV[128+f][i];
            float4 b0 = *(const float4*)&BETA[i][jh*8];
            float4 b1 = *(const float4*)&BETA[i][jh*8+4];
            acc[0] += v*b0.x; acc[1] += v*b0.y; acc[2] += v*b0.z; acc[3] += v*b0.w;
            acc[4] += v*b1.x; acc[5] += v*b1.y; acc[6] += v*b1.z; acc[7] += v*b1.w;
        }
        float g = gam[0];
        int j0 = jh*8;
        #pragma unroll
        for (int jj = 0; jj < 8; jj++) {
            int j = j0 + jj;
            if (j < S_) seq[n*KFS + f*S_ + j] = g*acc[jj] + X[f][j];
        }
    }
}

// ---------------- FC1: (3712,1920) @ (1920,128)^T + relu ----------------
__global__ __launch_bounds__(256) void fc1_kernel(
    const float* __restrict__ seq, const float* __restrict__ w,
    const float* __restrict__ bias, float* __restrict__ out)
{
    __shared__ float Sm[8*KFS];
    int n0 = blockIdx.x*8, tid = threadIdx.x;
    for (int i = tid; i < 8*KFS; i += 256) Sm[i] = seq[n0*KFS + i];
    __syncthreads();
    int h = tid & 127, rp = tid >> 7;
    float acc[4] = {0,0,0,0};
    const float4* wp = (const float4*)(w + h*KFS);
    #pragma unroll 4
    for (int k = 0; k < KFS/4; k++) {
        float4 wvv = wp[k];
        #pragma unroll
        for (int j = 0; j < 4; j++) {
            float4 sv = ((const float4*)&Sm[(rp*4+j)*KFS])[k];
            acc[j] += wvv.x*sv.x + wvv.y*sv.y + wvv.z*sv.z + wvv.w*sv.w;
        }
    }
    float bb2 = bias[h];
    #pragma unroll
    for (int j = 0; j < 4; j++)
        out[(n0 + rp*4 + j)*H_ + h] = fmaxf(acc[j] + bb2, 0.f);
}

// ---------------- 2-layer GRU + pred head ----------------
__global__ __launch_bounds__(768) void gru_kernel(
    const float* __restrict__ xin,  const float* __restrict__ wih,
    const float* __restrict__ whh,  const float* __restrict__ bih,
    const float* __restrict__ bhh,  const float* __restrict__ pw,
    const float* __restrict__ pb,   float* __restrict__ out)
{
    __shared__ float xh[H_], hh[H_], gi[3*H_], gh[3*H_], ys[L4_][H_];
    int b = blockIdx.x, tid = threadIdx.x;
    int mat = tid / 384, j = tid % 384;
    float4 wr[32];
    for (int layer = 0; layer < 2; layer++) {
        const float* wsrc = (mat ? whh : wih) + layer*384*128 + j*128;
        #pragma unroll
        for (int u = 0; u < 32; u++) wr[u] = ((const float4*)wsrc)[u];
        float bias = (mat ? bhh : bih)[layer*384 + j];
        if (tid < H_) hh[tid] = 0.f;
        __syncthreads();
        for (int t = 0; t < L4_; t++) {
            if (tid < H_) xh[tid] = (layer == 0) ? xin[(b*L4_+t)*H_ + tid] : ys[t][tid];
            __syncthreads();
            const float* src = mat ? hh : xh;
            float a0=0,a1=0,a2=0,a3=0;
            #pragma unroll
            for (int u = 0; u < 32; u++) {
                float4 xv = ((const float4*)src)[u];
                a0 += wr[u].x*xv.x; a1 += wr[u].y*xv.y;
                a2 += wr[u].z*xv.z; a3 += wr[u].w*xv.w;
            }
            float g = (a0+a1)+(a2+a3) + bias;
            if (mat) gh[j] = g; else gi[j] = g;
            __syncthreads();
            if (tid < H_) {
                int m = tid;
                float r = 1.f/(1.f+expf(-(gi[m]      + gh[m])));
                float z = 1.f/(1.f+expf(-(gi[m+128]  + gh[m+128])));
                float n = tanhf(gi[m+256] + r*gh[m+256]);
                float hnew = (1.f-z)*n + z*hh[m];
                hh[m] = hnew; ys[t][m] = hnew;
            }
            __syncthreads();
        }
    }
    if (tid < NC_) {
        float a = pb[tid];
        for (int k = 0; k < H_; k++) a += pw[tid*H_+k]*hh[k];
        out[b*NC_ + tid] = a;
    }
}

extern "C" void kernel_launch(void* const* d_in, const int* in_sizes, int n_in,
                              void* d_out, int out_size, void* d_ws, size_t ws_size,
                              hipStream_t stream) {
    const float* x    = (const float*)d_in[0];
    const float* w0   = (const float*)d_in[1];
    const float* wcs  = (const float*)d_in[2];
    const float* cb   = (const float*)d_in[3];
    const float* bg   = (const float*)d_in[4];
    const float* bb   = (const float*)d_in[5];
    const float* bm   = (const float*)d_in[6];
    const float* bv   = (const float*)d_in[7];
    const float* wq   = (const float*)d_in[8];
    const float* wk   = (const float*)d_in[9];
    const float* wv   = (const float*)d_in[10];
    const float* gam  = (const float*)d_in[11];
    const float* fw   = (const float*)d_in[12];
    const float* fb   = (const float*)d_in[13];
    const float* gwih = (const float*)d_in[14];
    const float* gwhh = (const float*)d_in[15];
    const float* gbih = (const float*)d_in[16];
    const float* gbhh = (const float*)d_in[17];
    const float* pw   = (const float*)d_in[18];
    const float* pb   = (const float*)d_in[19];
    float* out = (float*)d_out;
    uint32_t* wsu = (uint32_t*)d_ws;

    // workspace (4B word offsets):
    // aw (frag weights)       : 0        .. 61440
    // y1h planes (16000B/bs)  : 61440    .. +15,364,096   (y2 written in-place)
    // y1l planes              : 15425536 .. +15,364,096
    // P0 (y3 / seq)           : 30789632 .. +7,127,040
    // P1 (xs / f1)            : 37916672 .. +7,127,040    (end 45,043,712)
    ushort* aw  = (ushort*)wsu;
    char* y1h   = (char*)(wsu + 61440);
    char* y1l   = (char*)(wsu + 15425536);
    float* y3v  = (float*)(wsu + 30789632);
    float* seqv = (float*)(wsu + 30789632);
    float* xsv  = (float*)(wsu + 37916672);
    float* f1v  = (float*)(wsu + 37916672);

    prepack_kernel<<<240, 256, 0, stream>>>(wcs, aw);
    conv01_mfma<<<BS_, 512, 0, stream>>>(x, w0, aw, cb, bg, bb, bm, bv, y1h, y1l);
    conv2_mfma<<<BS_/2, 512, 0, stream>>>(aw, cb, bg, bb, bm, bv, y1h, y1l);
    conv3_mfma<<<BS_/4, 512, 0, stream>>>(aw, cb, bg, bb, bm, bv, y1h, y1l, y3v);
    transp_kernel<<<2*B_, 256, 0, stream>>>(y3v, xsv);
    attn_kernel<<<N_, 256, 0, stream>>>(xsv, wq, wk, wv, gam, seqv);
    fc1_kernel<<<N_/8, 256, 0, stream>>>(seqv, fw, fb, f1v);
    gru_kernel<<<B_, 768, 0, stream>>>(f1v, gwih, gwhh, gbih, gbhh, pw, pb, out);
}